// Round 2
// baseline (1800.919 us; speedup 1.0000x reference)
//
#include <hip/hip_runtime.h>
#include <math.h>

// ---------------------------------------------------------------------------
// FNO2d forward. Activations h stored as bf16 (halves footprint + traffic),
// all arithmetic and spectral intermediates fp32.
// Workspace layout:
//   bytes [0, 134217728)                  : h  bf16 [16][64][256][256]
//   then fp32 region fbase[] (float offsets):
//     f1  : [b*64+i][x][k2c]  8,388,608 floats (32 MiB)   (also G)
//     f2  : [m][b][i][2]        524,288 floats
//     c   : [m][b][o][2]        524,288 floats
//     wf  : fwd twiddle [y|x][16k][2]  8192 floats
//     wxi : inv-x twiddle [k1][x][2]   8192 floats
//     A,B : inv-y real basis [k2][y]   4096+4096 floats
// total = 134,217,728 + 4*9,461,760 = 172,064,768 bytes (~164.1 MiB)
// ---------------------------------------------------------------------------

typedef unsigned int   u32;
typedef unsigned short u16;

constexpr long HB_BYTES = 134217728;   // bf16 h region
constexpr long F1_OFF  = 0;
constexpr long F2_OFF  = F1_OFF + 8388608;
constexpr long C_OFF   = F2_OFF + 524288;
constexpr long WF_OFF  = C_OFF + 524288;
constexpr long WXI_OFF = WF_OFF + 8192;
constexpr long A_OFF   = WXI_OFF + 8192;
constexpr long B_OFF   = A_OFF + 4096;

__device__ __forceinline__ float gelu_exact(float v) {
    return 0.5f * v * (1.0f + erff(v * 0.70710678118654752440f));
}
__device__ __forceinline__ float bflo(u32 u) {            // bf16 elt 0 of pair
    return __uint_as_float(u << 16);
}
__device__ __forceinline__ float bfhi(u32 u) {            // bf16 elt 1 of pair
    return __uint_as_float(u & 0xffff0000u);
}
__device__ __forceinline__ u16 f2bf(float f) {            // fp32 -> bf16 RNE
    u32 u = __float_as_uint(f);
    u += 0x7fffu + ((u >> 16) & 1u);
    return (u16)(u >> 16);
}
__device__ __forceinline__ u32 pack2bf(float a, float b) {
    return (u32)f2bf(a) | ((u32)f2bf(b) << 16);
}

// --- twiddle / basis tables, fp64 trig with exact mod-256 reduction --------
__global__ __launch_bounds__(256) void k_tab(float* __restrict__ fb) {
    const int t = blockIdx.x * 256 + threadIdx.x;  // 0..12287
    if (t < 4096) {
        // wf[y][k][2] = e^{-2*pi*i*k*y/256} = (cos, -sin)
        const int y = t >> 4, k = t & 15;
        const int m = (k * y) & 255;
        double s, c; sincospi((double)m / 128.0, &s, &c);
        fb[WF_OFF + (long)t * 2]     = (float)c;
        fb[WF_OFF + (long)t * 2 + 1] = (float)(-s);
    } else if (t < 8192) {
        // wxi[k1][x][2] = e^{+2*pi*i*k1*x/256} = (cos, +sin)
        const int u = t - 4096;
        const int k1 = u >> 8, x = u & 255;
        const int m = (k1 * x) & 255;
        double s, c; sincospi((double)m / 128.0, &s, &c);
        fb[WXI_OFF + (long)u * 2]     = (float)c;
        fb[WXI_OFF + (long)u * 2 + 1] = (float)s;
    } else if (t < 12288) {
        // A[k2][y] = c_k2*cos, B[k2][y] = -c_k2*sin   (irfft real basis)
        const int u = t - 8192;
        const int k2 = u >> 8, y = u & 255;
        const int m = (k2 * y) & 255;
        double s, c; sincospi((double)m / 128.0, &s, &c);
        const float cc = (k2 == 0) ? 1.0f : 2.0f;
        fb[A_OFF + u] = cc * (float)c;
        fb[B_OFF + u] = -cc * (float)s;
    }
}

// --- lift: h[b][w][x][y] = fc0_b[w] + sum_c x[b][c][x][y]*fc0_w[w][c] ------
__global__ __launch_bounds__(256) void k_lift(const float* __restrict__ xin,
                                              const float* __restrict__ w0,
                                              const float* __restrict__ b0,
                                              u16* __restrict__ h) {
    __shared__ float ws0[192];
    __shared__ float bs0[64];
    const int tid = threadIdx.x;
    if (tid < 192) ws0[tid] = w0[tid];
    if (tid < 64)  bs0[tid] = b0[tid];
    __syncthreads();
    const int b = blockIdx.x >> 8, x = blockIdx.x & 255;
    const long pix = (((long)b * 3) * 256 + x) * 256 + tid;
    const float x0 = xin[pix];
    const float x1 = xin[pix + 65536];
    const float x2 = xin[pix + 131072];
    u16* hp = h + ((long)b * 64) * 65536 + x * 256 + tid;
    #pragma unroll 4
    for (int w = 0; w < 64; w++) {
        float v = bs0[w];
        v = fmaf(x0, ws0[w * 3],     v);
        v = fmaf(x1, ws0[w * 3 + 1], v);
        v = fmaf(x2, ws0[w * 3 + 2], v);
        hp[(long)w * 65536] = f2bf(v);
    }
}

// --- K1: F1[r][k2c] = sum_y h[r][y] * wf[y][k2]  (r = (b*64+i)*256 + x) ----
__global__ __launch_bounds__(256) void k_dfty(const u16* __restrict__ h,
                                              const float* __restrict__ wf,
                                              float* __restrict__ f1) {
    __shared__ __align__(16) float tab[8192];
    for (int t = threadIdx.x; t < 8192; t += 256) tab[t] = wf[t];
    __syncthreads();
    const int tid = threadIdx.x;
    const int k2 = tid & 15, rg = tid >> 4;
    const long r0 = (long)blockIdx.x * 64 + rg * 4;
    const u16* hp = h + r0 * 256;
    float ar[4] = {0, 0, 0, 0}, ai[4] = {0, 0, 0, 0};
    for (int y = 0; y < 256; y += 8) {
        uint4 q0 = *(const uint4*)(hp + y);
        uint4 q1 = *(const uint4*)(hp + 256 + y);
        uint4 q2 = *(const uint4*)(hp + 512 + y);
        uint4 q3 = *(const uint4*)(hp + 768 + y);
        const u32* a0 = (const u32*)&q0;
        const u32* a1 = (const u32*)&q1;
        const u32* a2 = (const u32*)&q2;
        const u32* a3 = (const u32*)&q3;
        #pragma unroll
        for (int u = 0; u < 4; u++) {
            const float2 tw0 = *(const float2*)(tab + (y + 2 * u) * 32 + k2 * 2);
            const float2 tw1 = *(const float2*)(tab + (y + 2 * u + 1) * 32 + k2 * 2);
            float e0 = bflo(a0[u]), e1 = bflo(a1[u]);
            float e2 = bflo(a2[u]), e3 = bflo(a3[u]);
            ar[0] = fmaf(e0, tw0.x, ar[0]); ai[0] = fmaf(e0, tw0.y, ai[0]);
            ar[1] = fmaf(e1, tw0.x, ar[1]); ai[1] = fmaf(e1, tw0.y, ai[1]);
            ar[2] = fmaf(e2, tw0.x, ar[2]); ai[2] = fmaf(e2, tw0.y, ai[2]);
            ar[3] = fmaf(e3, tw0.x, ar[3]); ai[3] = fmaf(e3, tw0.y, ai[3]);
            e0 = bfhi(a0[u]); e1 = bfhi(a1[u]);
            e2 = bfhi(a2[u]); e3 = bfhi(a3[u]);
            ar[0] = fmaf(e0, tw1.x, ar[0]); ai[0] = fmaf(e0, tw1.y, ai[0]);
            ar[1] = fmaf(e1, tw1.x, ar[1]); ai[1] = fmaf(e1, tw1.y, ai[1]);
            ar[2] = fmaf(e2, tw1.x, ar[2]); ai[2] = fmaf(e2, tw1.y, ai[2]);
            ar[3] = fmaf(e3, tw1.x, ar[3]); ai[3] = fmaf(e3, tw1.y, ai[3]);
        }
    }
    #pragma unroll
    for (int r = 0; r < 4; r++) {
        *(float2*)(f1 + (r0 + r) * 32 + k2 * 2) = make_float2(ar[r], ai[r]);
    }
}

// --- K2: F2[m][bi][2] = sum_x F1[bi][x][k2] * wf[x][k1]   (m = k1*16+k2) ---
__global__ __launch_bounds__(256) void k_dftx(const float* __restrict__ f1,
                                              const float* __restrict__ wf,
                                              float* __restrict__ f2) {
    const int tid = threadIdx.x;
    const int k1 = tid >> 4, k2 = tid & 15;
    const float* base = f1 + (long)blockIdx.x * 8192;
    float cr0 = 0, ci0 = 0, cr1 = 0, ci1 = 0;
    for (int x = 0; x < 256; x += 2) {
        const float2 Fa = *(const float2*)(base + x * 32 + k2 * 2);
        const float2 ta = *(const float2*)(wf + x * 32 + k1 * 2);
        cr0 = fmaf(Fa.x, ta.x, fmaf(-Fa.y, ta.y, cr0));
        ci0 = fmaf(Fa.y, ta.x, fmaf(Fa.x, ta.y, ci0));
        const float2 Fb = *(const float2*)(base + (x + 1) * 32 + k2 * 2);
        const float2 tb = *(const float2*)(wf + (x + 1) * 32 + k1 * 2);
        cr1 = fmaf(Fb.x, tb.x, fmaf(-Fb.y, tb.y, cr1));
        ci1 = fmaf(Fb.y, tb.x, fmaf(Fb.x, tb.y, ci1));
    }
    const int m = k1 * 16 + k2;
    *(float2*)(f2 + ((long)m * 1024 + blockIdx.x) * 2) =
        make_float2(cr0 + cr1, ci0 + ci1);
}

// --- K3: C[m][b][o] = sum_i F2[m][b][i] * sw[i][o][m] / 65536 --------------
__global__ __launch_bounds__(256) void k_mode(const float* __restrict__ f2,
                                              const float* __restrict__ sw,
                                              float* __restrict__ cc) {
    __shared__ __align__(16) float wsh[8192];   // [i*64+o][2], pre-scaled
    __shared__ __align__(16) float fsh[2048];   // [b*64+i][2]
    const int tid = threadIdx.x;
    const int m = blockIdx.x;
    const float scale = 1.0f / 65536.0f;
    for (int p = tid; p < 4096; p += 256) {
        const float2 w = *(const float2*)(sw + ((long)p * 256 + m) * 2);
        wsh[p * 2]     = w.x * scale;
        wsh[p * 2 + 1] = w.y * scale;
    }
    for (int t = tid; t < 2048; t += 256) fsh[t] = f2[(long)m * 2048 + t];
    __syncthreads();
    const int b = tid >> 4, o0 = (tid & 15) * 4;
    float re[4] = {0, 0, 0, 0}, im[4] = {0, 0, 0, 0};
    for (int i = 0; i < 64; i++) {
        const float2 F = *(const float2*)(fsh + (b * 64 + i) * 2);
        #pragma unroll
        for (int oo = 0; oo < 4; oo++) {
            const float2 W = *(const float2*)(wsh + (i * 64 + o0 + oo) * 2);
            re[oo] = fmaf(F.x, W.x, fmaf(-F.y, W.y, re[oo]));
            im[oo] = fmaf(F.x, W.y, fmaf(F.y, W.x, im[oo]));
        }
    }
    #pragma unroll
    for (int oo = 0; oo < 4; oo++) {
        *(float2*)(cc + ((long)m * 1024 + b * 64 + o0 + oo) * 2) =
            make_float2(re[oo], im[oo]);
    }
}

// --- K4: G[bo][x][k2c] = sum_k1 C[k1*16+k2][bo] * e^{+2 pi i k1 x/256} -----
__global__ __launch_bounds__(256) void k_invx(const float* __restrict__ cc,
                                              const float* __restrict__ wxi,
                                              float* __restrict__ g) {
    __shared__ __align__(16) float csh[512];    // [m][2]
    const int tid = threadIdx.x;
    const int blk = blockIdx.x;                 // b*64+o
    ((float2*)csh)[tid] = *(const float2*)(cc + ((long)tid * 1024 + blk) * 2);
    __syncthreads();
    const int x = tid;
    float ar[16], ai[16];
    #pragma unroll
    for (int k = 0; k < 16; k++) { ar[k] = 0; ai[k] = 0; }
    for (int k1 = 0; k1 < 16; k1++) {
        const float2 t = *(const float2*)(wxi + (k1 * 256 + x) * 2);
        #pragma unroll
        for (int k2 = 0; k2 < 16; k2++) {
            const float2 C = ((const float2*)csh)[k1 * 16 + k2];
            ar[k2] = fmaf(C.x, t.x, fmaf(-C.y, t.y, ar[k2]));
            ai[k2] = fmaf(C.x, t.y, fmaf(C.y, t.x, ai[k2]));
        }
    }
    float* ob = g + ((long)blk * 256 + x) * 32;
    #pragma unroll
    for (int k = 0; k < 16; k++) ((float2*)ob)[k] = make_float2(ar[k], ai[k]);
}

// --- K5: h[b][o][x][y] = gelu( inv-y-DFT(G) + conv1x1(h) + cb ), in place --
__global__ __launch_bounds__(256) void k_conv(u16* __restrict__ h,
                                              const float* __restrict__ g,
                                              const float* __restrict__ cw,
                                              const float* __restrict__ cb,
                                              const float* __restrict__ atab,
                                              const float* __restrict__ btab) {
    __shared__ __align__(16) float wsh[4096];   // [i][o] = cw[o][i]
    __shared__ float cbs[64];
    __shared__ __align__(16) float gsh[2048];   // [(k2*2+ri)][o]
    const int tid = threadIdx.x;
    const int b = blockIdx.x >> 8, x = blockIdx.x & 255;
    for (int t = tid; t < 4096; t += 256)
        wsh[(t & 63) * 64 + (t >> 6)] = cw[t];
    if (tid < 64) cbs[tid] = cb[tid];
    for (int t = tid; t < 2048; t += 256) {
        const int o = t >> 5, r = t & 31;
        gsh[r * 64 + o] = g[(((long)b * 64 + o) * 256 + x) * 32 + r];
    }
    __syncthreads();
    const int o0 = (tid >> 5) * 8, y0 = (tid & 31) * 8;
    float acc[8][8];
    #pragma unroll
    for (int a = 0; a < 8; a++)
        #pragma unroll
        for (int c = 0; c < 8; c++) acc[a][c] = 0.0f;
    // inverse-y DFT of the spectral branch
    for (int k2 = 0; k2 < 16; k2++) {
        float av[8], bv[8], gre[8], gim[8];
        *(float4*)(av)     = *(const float4*)(atab + k2 * 256 + y0);
        *(float4*)(av + 4) = *(const float4*)(atab + k2 * 256 + y0 + 4);
        *(float4*)(bv)     = *(const float4*)(btab + k2 * 256 + y0);
        *(float4*)(bv + 4) = *(const float4*)(btab + k2 * 256 + y0 + 4);
        *(float4*)(gre)     = *(const float4*)(gsh + (k2 * 2) * 64 + o0);
        *(float4*)(gre + 4) = *(const float4*)(gsh + (k2 * 2) * 64 + o0 + 4);
        *(float4*)(gim)     = *(const float4*)(gsh + (k2 * 2 + 1) * 64 + o0);
        *(float4*)(gim + 4) = *(const float4*)(gsh + (k2 * 2 + 1) * 64 + o0 + 4);
        #pragma unroll
        for (int oo = 0; oo < 8; oo++)
            #pragma unroll
            for (int yy = 0; yy < 8; yy++)
                acc[oo][yy] = fmaf(gre[oo], av[yy],
                              fmaf(gim[oo], bv[yy], acc[oo][yy]));
    }
    // conv1x1: h streamed from global (bf16, L1/L2-resident per block)
    const u16* hb = h + ((long)b * 64) * 65536 + x * 256 + y0;
    for (int i = 0; i < 64; i++) {
        uint4 q = *(const uint4*)(hb + (long)i * 65536);
        const u32* qa = (const u32*)&q;
        float hv[8], wv[8];
        hv[0] = bflo(qa[0]); hv[1] = bfhi(qa[0]);
        hv[2] = bflo(qa[1]); hv[3] = bfhi(qa[1]);
        hv[4] = bflo(qa[2]); hv[5] = bfhi(qa[2]);
        hv[6] = bflo(qa[3]); hv[7] = bfhi(qa[3]);
        *(float4*)(wv)     = *(const float4*)(wsh + i * 64 + o0);
        *(float4*)(wv + 4) = *(const float4*)(wsh + i * 64 + o0 + 4);
        #pragma unroll
        for (int oo = 0; oo < 8; oo++)
            #pragma unroll
            for (int yy = 0; yy < 8; yy++)
                acc[oo][yy] = fmaf(wv[oo], hv[yy], acc[oo][yy]);
    }
    __syncthreads();   // all reads of h complete before any in-place write
    #pragma unroll
    for (int oo = 0; oo < 8; oo++) {
        float ov[8];
        const float bias = cbs[o0 + oo];
        #pragma unroll
        for (int yy = 0; yy < 8; yy++)
            ov[yy] = gelu_exact(acc[oo][yy] + bias);
        u16* op = h + ((long)b * 64 + o0 + oo) * 65536 + x * 256 + y0;
        uint4 s;
        s.x = pack2bf(ov[0], ov[1]);
        s.y = pack2bf(ov[2], ov[3]);
        s.z = pack2bf(ov[4], ov[5]);
        s.w = pack2bf(ov[6], ov[7]);
        *(uint4*)op = s;
    }
}

// --- head: out = fc2( gelu( fc1(h) ) ) -------------------------------------
__global__ __launch_bounds__(256) void k_head(const u16* __restrict__ h,
                                              const float* __restrict__ w1,
                                              const float* __restrict__ b1,
                                              const float* __restrict__ w2,
                                              const float* __restrict__ b2,
                                              float* __restrict__ out) {
    __shared__ __align__(16) float w1sh[4096];  // [i][f] = w1[f][i]
    __shared__ float b1sh[64], w2sh[64];
    __shared__ __align__(16) float red[2048];   // [fg][y]
    const int tid = threadIdx.x;
    const int b = blockIdx.x >> 8, x = blockIdx.x & 255;
    for (int t = tid; t < 4096; t += 256)
        w1sh[(t & 63) * 64 + (t >> 6)] = w1[t];
    if (tid < 64) { b1sh[tid] = b1[tid]; w2sh[tid] = w2[tid]; }
    __syncthreads();
    const int fg = tid >> 5, yg = tid & 31;
    const int f0 = fg * 8, y0 = yg * 8;
    float acc[8][8];
    #pragma unroll
    for (int a = 0; a < 8; a++)
        #pragma unroll
        for (int c = 0; c < 8; c++) acc[a][c] = 0.0f;
    const u16* hb = h + ((long)b * 64) * 65536 + x * 256 + y0;
    for (int i = 0; i < 64; i++) {
        uint4 q = *(const uint4*)(hb + (long)i * 65536);
        const u32* qa = (const u32*)&q;
        float hv[8], wv[8];
        hv[0] = bflo(qa[0]); hv[1] = bfhi(qa[0]);
        hv[2] = bflo(qa[1]); hv[3] = bfhi(qa[1]);
        hv[4] = bflo(qa[2]); hv[5] = bfhi(qa[2]);
        hv[6] = bflo(qa[3]); hv[7] = bfhi(qa[3]);
        *(float4*)(wv)     = *(const float4*)(w1sh + i * 64 + f0);
        *(float4*)(wv + 4) = *(const float4*)(w1sh + i * 64 + f0 + 4);
        #pragma unroll
        for (int ff = 0; ff < 8; ff++)
            #pragma unroll
            for (int yy = 0; yy < 8; yy++)
                acc[ff][yy] = fmaf(wv[ff], hv[yy], acc[ff][yy]);
    }
    float p[8];
    #pragma unroll
    for (int yy = 0; yy < 8; yy++) p[yy] = 0.0f;
    #pragma unroll
    for (int ff = 0; ff < 8; ff++) {
        const float bb = b1sh[f0 + ff];
        const float ww = w2sh[f0 + ff];
        #pragma unroll
        for (int yy = 0; yy < 8; yy++)
            p[yy] = fmaf(ww, gelu_exact(acc[ff][yy] + bb), p[yy]);
    }
    *(float4*)(red + fg * 256 + y0)     = *(float4*)(p);
    *(float4*)(red + fg * 256 + y0 + 4) = *(float4*)(p + 4);
    __syncthreads();
    const int y = tid;
    float s = b2[0];
    #pragma unroll
    for (int q = 0; q < 8; q++) s += red[q * 256 + y];
    out[(long)blockIdx.x * 256 + y] = s;
}

extern "C" void kernel_launch(void* const* d_in, const int* in_sizes, int n_in,
                              void* d_out, int out_size, void* d_ws, size_t ws_size,
                              hipStream_t stream) {
    const float* x     = (const float*)d_in[0];
    const float* fc0_w = (const float*)d_in[1];
    const float* fc0_b = (const float*)d_in[2];
    const float* sw[4] = {(const float*)d_in[3], (const float*)d_in[4],
                          (const float*)d_in[5], (const float*)d_in[6]};
    const float* cwA[4] = {(const float*)d_in[7],  (const float*)d_in[9],
                           (const float*)d_in[11], (const float*)d_in[13]};
    const float* cbA[4] = {(const float*)d_in[8],  (const float*)d_in[10],
                           (const float*)d_in[12], (const float*)d_in[14]};
    const float* fc1_w = (const float*)d_in[15];
    const float* fc1_b = (const float*)d_in[16];
    const float* fc2_w = (const float*)d_in[17];
    const float* fc2_b = (const float*)d_in[18];

    u16*   h  = (u16*)d_ws;
    float* fb = (float*)((char*)d_ws + HB_BYTES);
    float* f1   = fb + F1_OFF;   // also G (f1 dead after k_dftx)
    float* f2   = fb + F2_OFF;
    float* cbuf = fb + C_OFF;
    float* wf   = fb + WF_OFF;
    float* wxi  = fb + WXI_OFF;
    float* atab = fb + A_OFF;
    float* btab = fb + B_OFF;

    k_tab<<<48, 256, 0, stream>>>(fb);
    k_lift<<<4096, 256, 0, stream>>>(x, fc0_w, fc0_b, h);
    for (int l = 0; l < 4; l++) {
        k_dfty<<<4096, 256, 0, stream>>>(h, wf, f1);
        k_dftx<<<1024, 256, 0, stream>>>(f1, wf, f2);
        k_mode<<<256, 256, 0, stream>>>(f2, sw[l], cbuf);
        k_invx<<<1024, 256, 0, stream>>>(cbuf, wxi, f1);  // writes G over f1
        k_conv<<<4096, 256, 0, stream>>>(h, f1, cwA[l], cbA[l], atab, btab);
    }
    k_head<<<4096, 256, 0, stream>>>(h, fc1_w, fc1_b, fc2_w, fc2_b,
                                     (float*)d_out);
}

// Round 3
// 1092.202 us; speedup vs baseline: 1.6489x; 1.6489x over previous
//
#include <hip/hip_runtime.h>
#include <math.h>

// ---------------------------------------------------------------------------
// FNO2d forward, MFMA-ized. h bf16; all matmuls on matrix cores (bf16 in,
// fp32 accumulate; conv & head weights split hi+lo bf16 for fp32-level
// precision on the dominant path; spectral path single-bf16).
// Fusions: DFT-y fused into lift/conv epilogue (h read once per layer);
// head fused into layer-4 conv (no final h write).
// Workspace (bytes):
//   h   bf16 [16][64][256][256]   @ 0          134,217,728
//   f1  bf16 [(b*64+i)*256+x][32] @ 134217728   16,777,216
//   G   bf16 [(b*64+o)][x][32]    @ 150994944   16,777,216
//   f2  fp32 [m][b][i][2]         @ 167772160    2,097,152
//   cc  fp32 [m][b][o][2]         @ 169869312    2,097,152
//   wf  fp32 [x][16k][2]          @ 171966464       32,768
//   wxi fp32 [k1][x][2]           @ 171999232       32,768
//   twf bf16 [k2c][y]             @ 172032000       16,384
//   bas bf16 [y][2k2+c]           @ 172048384       16,384
// total 172,064,768 B (identical to round-2 footprint, known to fit)
// ---------------------------------------------------------------------------

typedef unsigned int   u32;
typedef unsigned short u16;
typedef __attribute__((ext_vector_type(8))) __bf16 bf16x8;
typedef __attribute__((ext_vector_type(4))) float  f32x4;

constexpr long F1_B  = 134217728;
constexpr long G_B   = 150994944;
constexpr long F2_B  = 167772160;
constexpr long CC_B  = 169869312;
constexpr long WF_B  = 171966464;
constexpr long WXI_B = 171999232;
constexpr long TWF_B = 172032000;
constexpr long BAS_B = 172048384;

__device__ __forceinline__ float gelu_exact(float v) {
    return 0.5f * v * (1.0f + erff(v * 0.70710678118654752440f));
}
__device__ __forceinline__ float bflo(u32 u) { return __uint_as_float(u << 16); }
__device__ __forceinline__ float bfhi(u32 u) { return __uint_as_float(u & 0xffff0000u); }
__device__ __forceinline__ u16 f2bf(float f) {            // fp32 -> bf16 RNE
    u32 u = __float_as_uint(f);
    u += 0x7fffu + ((u >> 16) & 1u);
    return (u16)(u >> 16);
}
__device__ __forceinline__ u32 pack2bf(float a, float b) {
    return (u32)f2bf(a) | ((u32)f2bf(b) << 16);
}

// --- tables ----------------------------------------------------------------
__global__ __launch_bounds__(256) void k_tab(float* __restrict__ wf,
                                             float* __restrict__ wxi,
                                             u16* __restrict__ twf,
                                             u16* __restrict__ bas) {
    const int t = blockIdx.x * 256 + threadIdx.x;   // 0..24575
    if (t < 4096) {               // wf[x][k][2] = (cos, -sin)(2*pi*k*x/256)
        const int y = t >> 4, k = t & 15;
        const int m = (k * y) & 255;
        double s, c; sincospi((double)m / 128.0, &s, &c);
        wf[t * 2] = (float)c; wf[t * 2 + 1] = (float)(-s);
    } else if (t < 8192) {        // wxi[k1][x][2] = (cos, +sin)
        const int u = t - 4096;
        const int k1 = u >> 8, x = u & 255;
        const int m = (k1 * x) & 255;
        double s, c; sincospi((double)m / 128.0, &s, &c);
        wxi[u * 2] = (float)c; wxi[u * 2 + 1] = (float)s;
    } else if (t < 16384) {       // twf[k2c][y]: re=cos, im=-sin
        const int u = t - 8192;
        const int kc = u >> 8, y = u & 255;
        const int k2 = kc >> 1;
        const int m = (k2 * y) & 255;
        double s, c; sincospi((double)m / 128.0, &s, &c);
        twf[kc * 256 + y] = f2bf((kc & 1) ? (float)(-s) : (float)c);
    } else {                      // bas[y][2k2+c]: c_k2*cos / -c_k2*sin
        const int u = t - 16384;
        const int y = u >> 5, kc = u & 31;
        const int k2 = kc >> 1;
        const int m = (k2 * y) & 255;
        double s, c; sincospi((double)m / 128.0, &s, &c);
        const float cc = (k2 == 0) ? 1.0f : 2.0f;
        bas[y * 32 + kc] = f2bf((kc & 1) ? (float)(-cc * s) : (float)(cc * c));
    }
}

// --- shared F1 epilogue: F1[o][k2c] = sum_y out[o][y]*twf[y][k2c] ----------
// HO = out tile in LDS, [o][264] bf16 (row-padded). MFMA M=64,N=32,K=256.
__device__ __forceinline__ void f1_epilogue(const u16* HO, const u16* __restrict__ twf,
                                            u16* __restrict__ f1, int b, int x, int tid) {
    const int lane = tid & 63, wave = tid >> 6;
    const int quad = lane >> 4, col = lane & 15;
    f32x4 acc0 = {0.f, 0.f, 0.f, 0.f}, acc1 = {0.f, 0.f, 0.f, 0.f};
    const int m = wave * 16 + col;
    #pragma unroll
    for (int ks = 0; ks < 8; ks++) {
        bf16x8 af = *(const bf16x8*)(HO + m * 264 + ks * 32 + quad * 8);
        bf16x8 b0 = *(const bf16x8*)(twf + col * 256 + ks * 32 + quad * 8);
        bf16x8 b1 = *(const bf16x8*)(twf + (16 + col) * 256 + ks * 32 + quad * 8);
        acc0 = __builtin_amdgcn_mfma_f32_16x16x32_bf16(af, b0, acc0, 0, 0, 0);
        acc1 = __builtin_amdgcn_mfma_f32_16x16x32_bf16(af, b1, acc1, 0, 0, 0);
    }
    #pragma unroll
    for (int r = 0; r < 4; r++) {
        const int o = wave * 16 + quad * 4 + r;
        u16* dst = f1 + (((long)(b * 64 + o)) * 256 + x) * 32;
        dst[col]      = f2bf(acc0[r]);
        dst[16 + col] = f2bf(acc1[r]);
    }
}

// --- lift + F1 epilogue ----------------------------------------------------
__global__ __launch_bounds__(256) void k_lift(const float* __restrict__ xin,
                                              const float* __restrict__ w0,
                                              const float* __restrict__ b0,
                                              u16* __restrict__ h,
                                              const u16* __restrict__ twf,
                                              u16* __restrict__ f1) {
    __shared__ float ws0[192];
    __shared__ float bs0[64];
    __shared__ u16 HO[64 * 264];
    const int tid = threadIdx.x;
    if (tid < 192) ws0[tid] = w0[tid];
    if (tid < 64)  bs0[tid] = b0[tid];
    __syncthreads();
    const int b = blockIdx.x >> 8, x = blockIdx.x & 255;
    const long pix = (((long)b * 3) * 256 + x) * 256 + tid;
    const float x0 = xin[pix];
    const float x1 = xin[pix + 65536];
    const float x2 = xin[pix + 131072];
    u16* hp = h + ((long)b * 64) * 65536 + x * 256 + tid;
    #pragma unroll 4
    for (int w = 0; w < 64; w++) {
        float v = bs0[w];
        v = fmaf(x0, ws0[w * 3],     v);
        v = fmaf(x1, ws0[w * 3 + 1], v);
        v = fmaf(x2, ws0[w * 3 + 2], v);
        const u16 bf = f2bf(v);
        hp[(long)w * 65536] = bf;
        HO[w * 264 + tid] = bf;
    }
    __syncthreads();
    f1_epilogue(HO, twf, f1, b, x, tid);
}

// --- K2: F2[m][bi][2] = sum_x F1[bi][x][k2] * wf[x][k1]   (m = k1*16+k2) ---
__global__ __launch_bounds__(256) void k_dftx(const u16* __restrict__ f1,
                                              const float* __restrict__ wf,
                                              float* __restrict__ f2) {
    const int tid = threadIdx.x;
    const int k1 = tid >> 4, k2 = tid & 15;
    const u16* base = f1 + (long)blockIdx.x * 8192;
    float cr0 = 0, ci0 = 0, cr1 = 0, ci1 = 0;
    for (int x = 0; x < 256; x += 2) {
        const u32 wa = *(const u32*)(base + x * 32 + k2 * 2);
        const float2 ta = *(const float2*)(wf + x * 32 + k1 * 2);
        const float Far = bflo(wa), Fai = bfhi(wa);
        cr0 = fmaf(Far, ta.x, fmaf(-Fai, ta.y, cr0));
        ci0 = fmaf(Fai, ta.x, fmaf(Far, ta.y, ci0));
        const u32 wb = *(const u32*)(base + (x + 1) * 32 + k2 * 2);
        const float2 tb = *(const float2*)(wf + (x + 1) * 32 + k1 * 2);
        const float Fbr = bflo(wb), Fbi = bfhi(wb);
        cr1 = fmaf(Fbr, tb.x, fmaf(-Fbi, tb.y, cr1));
        ci1 = fmaf(Fbi, tb.x, fmaf(Fbr, tb.y, ci1));
    }
    const int m = k1 * 16 + k2;
    *(float2*)(f2 + ((long)m * 1024 + blockIdx.x) * 2) =
        make_float2(cr0 + cr1, ci0 + ci1);
}

// --- K3: C[m][b][o] = sum_i F2[m][b][i] * sw[i][o][m] / 65536 --------------
__global__ __launch_bounds__(256) void k_mode(const float* __restrict__ f2,
                                              const float* __restrict__ sw,
                                              float* __restrict__ cc) {
    __shared__ __align__(16) float wsh[8192];   // [i*64+o][2], pre-scaled
    __shared__ __align__(16) float fsh[2048];   // [b*64+i][2]
    const int tid = threadIdx.x;
    const int m = blockIdx.x;
    const float scale = 1.0f / 65536.0f;
    for (int p = tid; p < 4096; p += 256) {
        const float2 w = *(const float2*)(sw + ((long)p * 256 + m) * 2);
        wsh[p * 2]     = w.x * scale;
        wsh[p * 2 + 1] = w.y * scale;
    }
    for (int t = tid; t < 2048; t += 256) fsh[t] = f2[(long)m * 2048 + t];
    __syncthreads();
    const int b = tid >> 4, o0 = (tid & 15) * 4;
    float re[4] = {0, 0, 0, 0}, im[4] = {0, 0, 0, 0};
    for (int i = 0; i < 64; i++) {
        const float2 F = *(const float2*)(fsh + (b * 64 + i) * 2);
        #pragma unroll
        for (int oo = 0; oo < 4; oo++) {
            const float2 W = *(const float2*)(wsh + (i * 64 + o0 + oo) * 2);
            re[oo] = fmaf(F.x, W.x, fmaf(-F.y, W.y, re[oo]));
            im[oo] = fmaf(F.x, W.y, fmaf(F.y, W.x, im[oo]));
        }
    }
    #pragma unroll
    for (int oo = 0; oo < 4; oo++) {
        *(float2*)(cc + ((long)m * 1024 + b * 64 + o0 + oo) * 2) =
            make_float2(re[oo], im[oo]);
    }
}

// --- K4: G[bo][x][2k2+c] = sum_k1 C[k1*16+k2][bo] * e^{+2 pi i k1 x/256} ---
__global__ __launch_bounds__(256) void k_invx(const float* __restrict__ cc,
                                              const float* __restrict__ wxi,
                                              u16* __restrict__ g) {
    __shared__ __align__(16) float csh[512];    // [m][2]
    const int tid = threadIdx.x;
    const int blk = blockIdx.x;                 // b*64+o
    ((float2*)csh)[tid] = *(const float2*)(cc + ((long)tid * 1024 + blk) * 2);
    __syncthreads();
    const int x = tid;
    float ar[16], ai[16];
    #pragma unroll
    for (int k = 0; k < 16; k++) { ar[k] = 0; ai[k] = 0; }
    for (int k1 = 0; k1 < 16; k1++) {
        const float2 t = *(const float2*)(wxi + (k1 * 256 + x) * 2);
        #pragma unroll
        for (int k2 = 0; k2 < 16; k2++) {
            const float2 C = ((const float2*)csh)[k1 * 16 + k2];
            ar[k2] = fmaf(C.x, t.x, fmaf(-C.y, t.y, ar[k2]));
            ai[k2] = fmaf(C.x, t.y, fmaf(C.y, t.x, ai[k2]));
        }
    }
    u32 wbuf[16];
    #pragma unroll
    for (int k = 0; k < 16; k++) wbuf[k] = pack2bf(ar[k], ai[k]);
    u16* ob = g + ((long)blk * 256 + x) * 32;
    #pragma unroll
    for (int q = 0; q < 4; q++) *(uint4*)(ob + q * 8) = ((uint4*)wbuf)[q];
}

// --- conv phase 1 (shared by k_conv / k_conv_head) -------------------------
// Builds A = [w_hi(64) | w_lo(64) | g(32)] in AB[64][168], h^T in HO[y][72],
// then acc[mt][nt] = MFMA over K=160. Leaves barrier-synced LDS free for reuse.
__device__ __forceinline__ void conv_phase1(
    const u16* __restrict__ h, const u16* __restrict__ Gbf,
    const float* __restrict__ cw, const float* __restrict__ cb,
    const u16* __restrict__ bas,
    u16* AB, u16* HO, float* cbs,
    long hbase, int b, int x, int tid, f32x4 (*acc)[4])
{
    // weights: split hi+lo bf16
    for (int p = tid; p < 4096; p += 256) {
        const float f = cw[p];
        const u16 hi = f2bf(f);
        const u16 lo = f2bf(f - __uint_as_float((u32)hi << 16));
        AB[(p >> 6) * 168 + (p & 63)]      = hi;
        AB[(p >> 6) * 168 + 64 + (p & 63)] = lo;
    }
    // spectral g rows (bf16, interleaved re/im)
    {
        const int o = tid >> 2, cg = tid & 3;
        const uint4 q = *(const uint4*)(Gbf + (((long)(b * 64 + o)) * 256 + x) * 32 + cg * 8);
        *(uint4*)(AB + o * 168 + 128 + cg * 8) = q;
    }
    if (tid < 64) cbs[tid] = cb[tid];
    // h^T staging: [y][72]
    {
        const int i = tid & 63, yc = tid >> 6;
        const u16* hs = h + hbase + (long)i * 65536 + yc * 64;
        u16* d = HO + i;
        #pragma unroll
        for (int u = 0; u < 8; u++) {
            const uint4 q = *(const uint4*)(hs + u * 8);
            const int y0 = yc * 64 + u * 8;
            d[(y0 + 0) * 72] = (u16)q.x;  d[(y0 + 1) * 72] = (u16)(q.x >> 16);
            d[(y0 + 2) * 72] = (u16)q.y;  d[(y0 + 3) * 72] = (u16)(q.y >> 16);
            d[(y0 + 4) * 72] = (u16)q.z;  d[(y0 + 5) * 72] = (u16)(q.z >> 16);
            d[(y0 + 6) * 72] = (u16)q.w;  d[(y0 + 7) * 72] = (u16)(q.w >> 16);
        }
    }
    __syncthreads();
    const int lane = tid & 63, wave = tid >> 6;
    const int quad = lane >> 4, col = lane & 15;
    const int ybase = wave * 64;
    #pragma unroll
    for (int ks = 0; ks < 5; ks++) {
        bf16x8 bfr[4];
        if (ks < 4) {
            const int krow = (ks & 1) * 32 + quad * 8;
            #pragma unroll
            for (int nt = 0; nt < 4; nt++)
                bfr[nt] = *(const bf16x8*)(HO + (ybase + nt * 16 + col) * 72 + krow);
        } else {
            #pragma unroll
            for (int nt = 0; nt < 4; nt++)
                bfr[nt] = *(const bf16x8*)(bas + (ybase + nt * 16 + col) * 32 + quad * 8);
        }
        #pragma unroll
        for (int mt = 0; mt < 4; mt++) {
            const bf16x8 af = *(const bf16x8*)(AB + (mt * 16 + col) * 168 + ks * 32 + quad * 8);
            #pragma unroll
            for (int nt = 0; nt < 4; nt++)
                acc[mt][nt] = __builtin_amdgcn_mfma_f32_16x16x32_bf16(af, bfr[nt], acc[mt][nt], 0, 0, 0);
        }
    }
    __syncthreads();   // phase-1 LDS reads complete; AB/HO reusable
}

// --- K5 (layers 1-3): h = gelu(spec + conv + cb) in place, + F1 epilogue ---
__global__ __launch_bounds__(256) void k_conv(u16* __restrict__ h,
                                              const u16* __restrict__ Gbf,
                                              const float* __restrict__ cw,
                                              const float* __restrict__ cb,
                                              const u16* __restrict__ bas,
                                              const u16* __restrict__ twf,
                                              u16* __restrict__ f1) {
    __shared__ u16 AB[64 * 168];
    __shared__ u16 HO[18432];
    __shared__ float cbs[64];
    const int tid = threadIdx.x;
    const int b = blockIdx.x >> 8, x = blockIdx.x & 255;
    const long hbase = (long)b * 4194304 + x * 256;
    f32x4 acc[4][4];
    const f32x4 z = {0.f, 0.f, 0.f, 0.f};
    #pragma unroll
    for (int i = 0; i < 4; i++)
        #pragma unroll
        for (int j = 0; j < 4; j++) acc[i][j] = z;
    conv_phase1(h, Gbf, cw, cb, bas, AB, HO, cbs, hbase, b, x, tid, acc);
    const int lane = tid & 63, wave = tid >> 6;
    const int quad = lane >> 4, col = lane & 15;
    const int ybase = wave * 64;
    // out tile -> HO[o][264] bf16
    #pragma unroll
    for (int mt = 0; mt < 4; mt++)
        #pragma unroll
        for (int nt = 0; nt < 4; nt++)
            #pragma unroll
            for (int r = 0; r < 4; r++) {
                const int o = mt * 16 + quad * 4 + r;
                const int y = ybase + nt * 16 + col;
                HO[o * 264 + y] = f2bf(gelu_exact(acc[mt][nt][r] + cbs[o]));
            }
    __syncthreads();
    // coalesced copy HO -> global h (in place; own slice only)
    {
        const int o = tid >> 2, cg = tid & 3;
        u16* dh = h + hbase + (long)o * 65536 + cg * 64;
        const u16* so = HO + o * 264 + cg * 64;
        #pragma unroll
        for (int u = 0; u < 8; u++)
            *(uint4*)(dh + u * 8) = *(const uint4*)(so + u * 8);
    }
    f1_epilogue(HO, twf, f1, b, x, tid);
}

// --- K5 (layer 4): conv + fused head, writes d_out only --------------------
__global__ __launch_bounds__(256) void k_conv_head(const u16* __restrict__ h,
                                                   const u16* __restrict__ Gbf,
                                                   const float* __restrict__ cw,
                                                   const float* __restrict__ cb,
                                                   const u16* __restrict__ bas,
                                                   const float* __restrict__ w1,
                                                   const float* __restrict__ b1,
                                                   const float* __restrict__ w2,
                                                   const float* __restrict__ b2,
                                                   float* __restrict__ out) {
    __shared__ u16 AB[64 * 168];
    __shared__ u16 HO[18432];
    __shared__ float cbs[64];
    __shared__ float b1s[64], w2s[64];
    const int tid = threadIdx.x;
    const int b = blockIdx.x >> 8, x = blockIdx.x & 255;
    const long hbase = (long)b * 4194304 + x * 256;
    const float bias2 = b2[0];
    f32x4 acc[4][4];
    const f32x4 z = {0.f, 0.f, 0.f, 0.f};
    #pragma unroll
    for (int i = 0; i < 4; i++)
        #pragma unroll
        for (int j = 0; j < 4; j++) acc[i][j] = z;
    conv_phase1(h, Gbf, cw, cb, bas, AB, HO, cbs, hbase, b, x, tid, acc);
    const int lane = tid & 63, wave = tid >> 6;
    const int quad = lane >> 4, col = lane & 15;
    const int ybase = wave * 64;
    // out tile transposed -> HO[y][72] bf16 (B-operand for head: K = o)
    #pragma unroll
    for (int mt = 0; mt < 4; mt++)
        #pragma unroll
        for (int nt = 0; nt < 4; nt++)
            #pragma unroll
            for (int r = 0; r < 4; r++) {
                const int o = mt * 16 + quad * 4 + r;
                const int y = ybase + nt * 16 + col;
                HO[y * 72 + o] = f2bf(gelu_exact(acc[mt][nt][r] + cbs[o]));
            }
    // stage w1 hi/lo into AB (free after phase-1 barrier)
    for (int p = tid; p < 4096; p += 256) {
        const float f = w1[p];
        const u16 hi = f2bf(f);
        const u16 lo = f2bf(f - __uint_as_float((u32)hi << 16));
        AB[(p >> 6) * 168 + (p & 63)]      = hi;
        AB[(p >> 6) * 168 + 64 + (p & 63)] = lo;
    }
    if (tid < 64) { b1s[tid] = b1[tid]; w2s[tid] = w2[tid]; }
    __syncthreads();
    // head MFMA: M=64 f, N=256 y, K=128 (o hi | o lo)
    f32x4 acc2[4][4];
    #pragma unroll
    for (int i = 0; i < 4; i++)
        #pragma unroll
        for (int j = 0; j < 4; j++) acc2[i][j] = z;
    #pragma unroll
    for (int ks = 0; ks < 4; ks++) {
        const int krow = (ks & 1) * 32 + quad * 8;
        bf16x8 bfr[4];
        #pragma unroll
        for (int nt = 0; nt < 4; nt++)
            bfr[nt] = *(const bf16x8*)(HO + (ybase + nt * 16 + col) * 72 + krow);
        #pragma unroll
        for (int mt = 0; mt < 4; mt++) {
            const bf16x8 af = *(const bf16x8*)(AB + (mt * 16 + col) * 168 + ks * 32 + quad * 8);
            #pragma unroll
            for (int nt = 0; nt < 4; nt++)
                acc2[mt][nt] = __builtin_amdgcn_mfma_f32_16x16x32_bf16(af, bfr[nt], acc2[mt][nt], 0, 0, 0);
        }
    }
    // gelu, dot w2 over f (rows), cross-quad shuffle reduce
    float p4[4] = {0.f, 0.f, 0.f, 0.f};
    #pragma unroll
    for (int mt = 0; mt < 4; mt++)
        #pragma unroll
        for (int r = 0; r < 4; r++) {
            const int f = mt * 16 + quad * 4 + r;
            const float bb = b1s[f], ww = w2s[f];
            #pragma unroll
            for (int nt = 0; nt < 4; nt++)
                p4[nt] = fmaf(ww, gelu_exact(acc2[mt][nt][r] + bb), p4[nt]);
        }
    #pragma unroll
    for (int nt = 0; nt < 4; nt++) {
        p4[nt] += __shfl_xor(p4[nt], 16);
        p4[nt] += __shfl_xor(p4[nt], 32);
    }
    out[(long)b * 65536 + x * 256 + ybase + lane] = p4[quad] + bias2;
}

extern "C" void kernel_launch(void* const* d_in, const int* in_sizes, int n_in,
                              void* d_out, int out_size, void* d_ws, size_t ws_size,
                              hipStream_t stream) {
    const float* x     = (const float*)d_in[0];
    const float* fc0_w = (const float*)d_in[1];
    const float* fc0_b = (const float*)d_in[2];
    const float* sw[4] = {(const float*)d_in[3], (const float*)d_in[4],
                          (const float*)d_in[5], (const float*)d_in[6]};
    const float* cwA[4] = {(const float*)d_in[7],  (const float*)d_in[9],
                           (const float*)d_in[11], (const float*)d_in[13]};
    const float* cbA[4] = {(const float*)d_in[8],  (const float*)d_in[10],
                           (const float*)d_in[12], (const float*)d_in[14]};
    const float* fc1_w = (const float*)d_in[15];
    const float* fc1_b = (const float*)d_in[16];
    const float* fc2_w = (const float*)d_in[17];
    const float* fc2_b = (const float*)d_in[18];

    char* base = (char*)d_ws;
    u16*   h    = (u16*)base;
    u16*   f1   = (u16*)(base + F1_B);
    u16*   Gbf  = (u16*)(base + G_B);
    float* f2   = (float*)(base + F2_B);
    float* cbuf = (float*)(base + CC_B);
    float* wf   = (float*)(base + WF_B);
    float* wxi  = (float*)(base + WXI_B);
    u16*   twf  = (u16*)(base + TWF_B);
    u16*   bas  = (u16*)(base + BAS_B);

    k_tab<<<96, 256, 0, stream>>>(wf, wxi, twf, bas);
    k_lift<<<4096, 256, 0, stream>>>(x, fc0_w, fc0_b, h, twf, f1);
    for (int l = 0; l < 4; l++) {
        k_dftx<<<1024, 256, 0, stream>>>(f1, wf, f2);
        k_mode<<<256, 256, 0, stream>>>(f2, sw[l], cbuf);
        k_invx<<<1024, 256, 0, stream>>>(cbuf, wxi, Gbf);
        if (l < 3) {
            k_conv<<<4096, 256, 0, stream>>>(h, Gbf, cwA[l], cbA[l], bas, twf, f1);
        } else {
            k_conv_head<<<4096, 256, 0, stream>>>(h, Gbf, cwA[3], cbA[3], bas,
                                                  fc1_w, fc1_b, fc2_w, fc2_b,
                                                  (float*)d_out);
        }
    }
}

// Round 4
// 984.907 us; speedup vs baseline: 1.8285x; 1.1089x over previous
//
#include <hip/hip_runtime.h>
#include <math.h>

// ---------------------------------------------------------------------------
// FNO2d forward, MFMA everywhere, channels-last activations.
// h stored [b][x][y][i] bf16 so MFMA B-fragments (k=i contiguous) load
// DIRECTLY from global, and C-tiles (4 contiguous o per lane) store DIRECTLY
// back — no LDS transposes for the conv path. Weights hi/lo-split once per
// layer into global scratch (L2-hot A-fragments). Only the fused DFT-y
// epilogue round-trips LDS (vector writes, scalar B-side reads).
// Workspace (bytes):
//   h    bf16 [16][256][256][64]  @ 0          134,217,728
//   f1   bf16 [(b*64+i)*256+x][32]@ 134217728   16,777,216
//   G    bf16 [(b*64+o)][x][32]   @ 150994944   16,777,216
//   f2   fp32 [m][b][i][2]        @ 167772160    2,097,152
//   cc   fp32 [m][b][o][2]        @ 169869312    2,097,152
//   wf   fp32 [x][16k][2]         @ 171966464       32,768
//   wxi  fp32 [k1][x][2]          @ 171999232       32,768
//   twf  bf16 [k2c][y]            @ 172032000       16,384
//   bas  bf16 [y][2k2+c]          @ 172048384       16,384
//   wsp  bf16 [5][64][hi64|lo64]  @ 172064768       81,920
// total 172,146,688 B (~164.2 MiB)
// ---------------------------------------------------------------------------

typedef unsigned int   u32;
typedef unsigned short u16;
typedef __attribute__((ext_vector_type(8))) __bf16 bf16x8;
typedef __attribute__((ext_vector_type(4))) float  f32x4;

constexpr long F1_B  = 134217728;
constexpr long G_B   = 150994944;
constexpr long F2_B  = 167772160;
constexpr long CC_B  = 169869312;
constexpr long WF_B  = 171966464;
constexpr long WXI_B = 171999232;
constexpr long TWF_B = 172032000;
constexpr long BAS_B = 172048384;
constexpr long WSP_B = 172064768;

constexpr int HOP = 76;   // HOyo row pad (u16): 152 B ≡ 0 mod 8, bank-spread

union BU { uint2 u2[2]; uint4 u4; bf16x8 v; u16 s[8]; };

__device__ __forceinline__ float gelu_exact(float v) {
    return 0.5f * v * (1.0f + erff(v * 0.70710678118654752440f));
}
__device__ __forceinline__ float bflo(u32 u) { return __uint_as_float(u << 16); }
__device__ __forceinline__ float bfhi(u32 u) { return __uint_as_float(u & 0xffff0000u); }
__device__ __forceinline__ u16 f2bf(float f) {            // fp32 -> bf16 RNE
    u32 u = __float_as_uint(f);
    u += 0x7fffu + ((u >> 16) & 1u);
    return (u16)(u >> 16);
}
__device__ __forceinline__ u32 pack2bf(float a, float b) {
    return (u32)f2bf(a) | ((u32)f2bf(b) << 16);
}

// --- tables ----------------------------------------------------------------
__global__ __launch_bounds__(256) void k_tab(float* __restrict__ wf,
                                             float* __restrict__ wxi,
                                             u16* __restrict__ twf,
                                             u16* __restrict__ bas) {
    const int t = blockIdx.x * 256 + threadIdx.x;   // 0..24575
    if (t < 4096) {               // wf[x][k][2] = (cos, -sin)(2*pi*k*x/256)
        const int y = t >> 4, k = t & 15;
        const int m = (k * y) & 255;
        double s, c; sincospi((double)m / 128.0, &s, &c);
        wf[t * 2] = (float)c; wf[t * 2 + 1] = (float)(-s);
    } else if (t < 8192) {        // wxi[k1][x][2] = (cos, +sin)
        const int u = t - 4096;
        const int k1 = u >> 8, x = u & 255;
        const int m = (k1 * x) & 255;
        double s, c; sincospi((double)m / 128.0, &s, &c);
        wxi[u * 2] = (float)c; wxi[u * 2 + 1] = (float)s;
    } else if (t < 16384) {       // twf[k2c][y]: re=cos, im=-sin
        const int u = t - 8192;
        const int kc = u >> 8, y = u & 255;
        const int k2 = kc >> 1;
        const int m = (k2 * y) & 255;
        double s, c; sincospi((double)m / 128.0, &s, &c);
        twf[kc * 256 + y] = f2bf((kc & 1) ? (float)(-s) : (float)c);
    } else {                      // bas[y][2k2+c]: c_k2*cos / -c_k2*sin
        const int u = t - 16384;
        const int y = u >> 5, kc = u & 31;
        const int k2 = kc >> 1;
        const int m = (k2 * y) & 255;
        double s, c; sincospi((double)m / 128.0, &s, &c);
        const float cc = (k2 == 0) ? 1.0f : 2.0f;
        bas[y * 32 + kc] = f2bf((kc & 1) ? (float)(-cc * s) : (float)(cc * c));
    }
}

// --- weight split: wsp[w][o][0..63]=hi, [o][64..127]=lo --------------------
__global__ __launch_bounds__(256) void k_wsplit(const float* __restrict__ c1,
                                                const float* __restrict__ c2,
                                                const float* __restrict__ c3,
                                                const float* __restrict__ c4,
                                                const float* __restrict__ f1w,
                                                u16* __restrict__ wsp) {
    const int t = blockIdx.x * 256 + threadIdx.x;   // < 20480
    const int w = t >> 12, p = t & 4095;
    const float* src = (w == 0) ? c1 : (w == 1) ? c2 : (w == 2) ? c3
                     : (w == 3) ? c4 : f1w;
    const float f = src[p];
    const u16 hi = f2bf(f);
    const u16 lo = f2bf(f - __uint_as_float((u32)hi << 16));
    u16* dst = wsp + w * 8192 + (p >> 6) * 128 + (p & 63);
    dst[0]  = hi;
    dst[64] = lo;
}

// --- fused DFT-y epilogue: f1[(b*64+o)*256+x][kc] = sum_y HOyo[y][o]*twf ---
// MFMA: D[m=kc(32)][n=o(64)], A = twf (global, contiguous), B from HOyo.
__device__ __forceinline__ void f1t_epilogue(const u16* HOyo,
                                             const u16* __restrict__ twf,
                                             u16* __restrict__ f1,
                                             int b, int x, int tid) {
    const int lane = tid & 63, wave = tid >> 6;
    const int quad = lane >> 4, col = lane & 15;
    const int o = wave * 16 + col;
    f32x4 a0 = {0.f, 0.f, 0.f, 0.f}, a1 = {0.f, 0.f, 0.f, 0.f};
    #pragma unroll
    for (int ks = 0; ks < 8; ks++) {
        const int kb = ks * 32 + quad * 8;
        BU bb;
        #pragma unroll
        for (int j = 0; j < 8; j++) bb.s[j] = HOyo[(kb + j) * HOP + o];
        const bf16x8 af0 = *(const bf16x8*)(twf + col * 256 + kb);
        const bf16x8 af1 = *(const bf16x8*)(twf + (16 + col) * 256 + kb);
        a0 = __builtin_amdgcn_mfma_f32_16x16x32_bf16(af0, bb.v, a0, 0, 0, 0);
        a1 = __builtin_amdgcn_mfma_f32_16x16x32_bf16(af1, bb.v, a1, 0, 0, 0);
    }
    u16* dst = f1 + (((long)(b * 64 + o)) * 256 + x) * 32 + quad * 4;
    uint2 w;
    w.x = pack2bf(a0[0], a0[1]); w.y = pack2bf(a0[2], a0[3]);
    *(uint2*)dst = w;
    w.x = pack2bf(a1[0], a1[1]); w.y = pack2bf(a1[2], a1[3]);
    *(uint2*)(dst + 16) = w;
}

// --- lift: h[b][x][y][i] = fc0(x), channels-last, + DFT-y epilogue ---------
__global__ __launch_bounds__(256) void k_lift(const float* __restrict__ xin,
                                              const float* __restrict__ w0,
                                              const float* __restrict__ b0,
                                              u16* __restrict__ h,
                                              const u16* __restrict__ twf,
                                              u16* __restrict__ f1) {
    __shared__ float ws0[192], bs0[64];
    __shared__ u16 HOyo[256 * HOP];
    const int tid = threadIdx.x;
    if (tid < 192) ws0[tid] = w0[tid];
    if (tid < 64)  bs0[tid] = b0[tid];
    __syncthreads();
    const int b = blockIdx.x >> 8, x = blockIdx.x & 255;
    const long pix = (((long)b * 3) * 256 + x) * 256 + tid;
    const float x0 = xin[pix];
    const float x1 = xin[pix + 65536];
    const float x2 = xin[pix + 131072];
    u32 pr[32];
    #pragma unroll
    for (int w = 0; w < 64; w += 2) {
        float v0 = bs0[w], v1 = bs0[w + 1];
        v0 = fmaf(x0, ws0[w * 3],     v0);  v1 = fmaf(x0, ws0[w * 3 + 3], v1);
        v0 = fmaf(x1, ws0[w * 3 + 1], v0);  v1 = fmaf(x1, ws0[w * 3 + 4], v1);
        v0 = fmaf(x2, ws0[w * 3 + 2], v0);  v1 = fmaf(x2, ws0[w * 3 + 5], v1);
        pr[w >> 1] = pack2bf(v0, v1);
    }
    u16* hrow = h + (((long)(b * 256 + x)) << 14) + (long)tid * 64;
    #pragma unroll
    for (int q = 0; q < 8; q++) *(uint4*)(hrow + q * 8) = ((uint4*)pr)[q];
    #pragma unroll
    for (int q = 0; q < 16; q++)
        *(uint2*)(HOyo + tid * HOP + q * 4) = ((uint2*)pr)[q];
    __syncthreads();
    f1t_epilogue(HOyo, twf, f1, b, x, tid);
}

// --- K2: F2[m][bi][2] = sum_x F1[bi][x][k2] * wf[x][k1]   (m = k1*16+k2) ---
__global__ __launch_bounds__(256) void k_dftx(const u16* __restrict__ f1,
                                              const float* __restrict__ wf,
                                              float* __restrict__ f2) {
    const int tid = threadIdx.x;
    const int k1 = tid >> 4, k2 = tid & 15;
    const u16* base = f1 + (long)blockIdx.x * 8192;
    float cr0 = 0, ci0 = 0, cr1 = 0, ci1 = 0;
    for (int x = 0; x < 256; x += 2) {
        const u32 wa = *(const u32*)(base + x * 32 + k2 * 2);
        const float2 ta = *(const float2*)(wf + x * 32 + k1 * 2);
        const float Far = bflo(wa), Fai = bfhi(wa);
        cr0 = fmaf(Far, ta.x, fmaf(-Fai, ta.y, cr0));
        ci0 = fmaf(Fai, ta.x, fmaf(Far, ta.y, ci0));
        const u32 wb = *(const u32*)(base + (x + 1) * 32 + k2 * 2);
        const float2 tb = *(const float2*)(wf + (x + 1) * 32 + k1 * 2);
        const float Fbr = bflo(wb), Fbi = bfhi(wb);
        cr1 = fmaf(Fbr, tb.x, fmaf(-Fbi, tb.y, cr1));
        ci1 = fmaf(Fbi, tb.x, fmaf(Fbr, tb.y, ci1));
    }
    const int m = k1 * 16 + k2;
    *(float2*)(f2 + ((long)m * 1024 + blockIdx.x) * 2) =
        make_float2(cr0 + cr1, ci0 + ci1);
}

// --- K3: C[m][b][o] = sum_i F2[m][b][i] * sw[i][o][m] / 65536 --------------
__global__ __launch_bounds__(256) void k_mode(const float* __restrict__ f2,
                                              const float* __restrict__ sw,
                                              float* __restrict__ cc) {
    __shared__ __align__(16) float wsh[8192];   // [i*64+o][2], pre-scaled
    __shared__ __align__(16) float fsh[2048];   // [b*64+i][2]
    const int tid = threadIdx.x;
    const int m = blockIdx.x;
    const float scale = 1.0f / 65536.0f;
    for (int p = tid; p < 4096; p += 256) {
        const float2 w = *(const float2*)(sw + ((long)p * 256 + m) * 2);
        wsh[p * 2]     = w.x * scale;
        wsh[p * 2 + 1] = w.y * scale;
    }
    for (int t = tid; t < 2048; t += 256) fsh[t] = f2[(long)m * 2048 + t];
    __syncthreads();
    const int b = tid >> 4, o0 = (tid & 15) * 4;
    float re[4] = {0, 0, 0, 0}, im[4] = {0, 0, 0, 0};
    for (int i = 0; i < 64; i++) {
        const float2 F = *(const float2*)(fsh + (b * 64 + i) * 2);
        #pragma unroll
        for (int oo = 0; oo < 4; oo++) {
            const float2 W = *(const float2*)(wsh + (i * 64 + o0 + oo) * 2);
            re[oo] = fmaf(F.x, W.x, fmaf(-F.y, W.y, re[oo]));
            im[oo] = fmaf(F.x, W.y, fmaf(F.y, W.x, im[oo]));
        }
    }
    #pragma unroll
    for (int oo = 0; oo < 4; oo++) {
        *(float2*)(cc + ((long)m * 1024 + b * 64 + o0 + oo) * 2) =
            make_float2(re[oo], im[oo]);
    }
}

// --- K4: G[bo][x][2k2+c] = sum_k1 C[k1*16+k2][bo] * e^{+2 pi i k1 x/256} ---
__global__ __launch_bounds__(256) void k_invx(const float* __restrict__ cc,
                                              const float* __restrict__ wxi,
                                              u16* __restrict__ g) {
    __shared__ __align__(16) float csh[512];    // [m][2]
    const int tid = threadIdx.x;
    const int blk = blockIdx.x;                 // b*64+o
    ((float2*)csh)[tid] = *(const float2*)(cc + ((long)tid * 1024 + blk) * 2);
    __syncthreads();
    const int x = tid;
    float ar[16], ai[16];
    #pragma unroll
    for (int k = 0; k < 16; k++) { ar[k] = 0; ai[k] = 0; }
    for (int k1 = 0; k1 < 16; k1++) {
        const float2 t = *(const float2*)(wxi + (k1 * 256 + x) * 2);
        #pragma unroll
        for (int k2 = 0; k2 < 16; k2++) {
            const float2 C = ((const float2*)csh)[k1 * 16 + k2];
            ar[k2] = fmaf(C.x, t.x, fmaf(-C.y, t.y, ar[k2]));
            ai[k2] = fmaf(C.x, t.y, fmaf(C.y, t.x, ai[k2]));
        }
    }
    u32 wbuf[16];
    #pragma unroll
    for (int k = 0; k < 16; k++) wbuf[k] = pack2bf(ar[k], ai[k]);
    u16* ob = g + ((long)blk * 256 + x) * 32;
    #pragma unroll
    for (int q = 0; q < 4; q++) *(uint4*)(ob + q * 8) = ((uint4*)wbuf)[q];
}

// --- conv phase 1: acc[mt][nt] = W_hi.h + W_lo.h + g.bas  (all direct) -----
__device__ __forceinline__ void conv_phase1(const u16* __restrict__ h, long hbase,
                                            const u16* __restrict__ Gbf,
                                            const u16* __restrict__ wsp,
                                            const u16* __restrict__ bas,
                                            int b, int x, int tid, f32x4 (*acc)[4]) {
    const int lane = tid & 63, wave = tid >> 6;
    const int quad = lane >> 4, col = lane & 15;
    #pragma unroll
    for (int ks = 0; ks < 2; ks++) {
        bf16x8 B[4], Ah[4], Al[4];
        #pragma unroll
        for (int nt = 0; nt < 4; nt++) {
            const int y = wave * 64 + nt * 16 + col;
            B[nt] = *(const bf16x8*)(h + hbase + (long)y * 64 + ks * 32 + quad * 8);
        }
        #pragma unroll
        for (int mt = 0; mt < 4; mt++) {
            Ah[mt] = *(const bf16x8*)(wsp + (mt * 16 + col) * 128 + ks * 32 + quad * 8);
            Al[mt] = *(const bf16x8*)(wsp + (mt * 16 + col) * 128 + 64 + ks * 32 + quad * 8);
        }
        #pragma unroll
        for (int mt = 0; mt < 4; mt++)
            #pragma unroll
            for (int nt = 0; nt < 4; nt++) {
                acc[mt][nt] = __builtin_amdgcn_mfma_f32_16x16x32_bf16(Ah[mt], B[nt], acc[mt][nt], 0, 0, 0);
                acc[mt][nt] = __builtin_amdgcn_mfma_f32_16x16x32_bf16(Al[mt], B[nt], acc[mt][nt], 0, 0, 0);
            }
    }
    {   // spectral: A = g rows, B = bas
        bf16x8 B[4], Ag[4];
        #pragma unroll
        for (int nt = 0; nt < 4; nt++) {
            const int y = wave * 64 + nt * 16 + col;
            B[nt] = *(const bf16x8*)(bas + y * 32 + quad * 8);
        }
        #pragma unroll
        for (int mt = 0; mt < 4; mt++)
            Ag[mt] = *(const bf16x8*)(Gbf + (((long)(b * 64 + mt * 16 + col)) * 256 + x) * 32 + quad * 8);
        #pragma unroll
        for (int mt = 0; mt < 4; mt++)
            #pragma unroll
            for (int nt = 0; nt < 4; nt++)
                acc[mt][nt] = __builtin_amdgcn_mfma_f32_16x16x32_bf16(Ag[mt], B[nt], acc[mt][nt], 0, 0, 0);
    }
}

// --- K5 (layers 1-3): h = gelu(spec+conv+cb) in place + DFT-y epilogue -----
__global__ __launch_bounds__(256, 3) void k_conv(u16* __restrict__ h,
                                                 const u16* __restrict__ Gbf,
                                                 const u16* __restrict__ wsp,
                                                 const float* __restrict__ cb,
                                                 const u16* __restrict__ bas,
                                                 const u16* __restrict__ twf,
                                                 u16* __restrict__ f1) {
    __shared__ u16 HOyo[256 * HOP];
    __shared__ float cbs[64];
    const int tid = threadIdx.x;
    const int b = blockIdx.x >> 8, x = blockIdx.x & 255;
    const long hbase = ((long)(b * 256 + x)) << 14;
    if (tid < 64) cbs[tid] = cb[tid];
    f32x4 acc[4][4];
    const f32x4 z = {0.f, 0.f, 0.f, 0.f};
    #pragma unroll
    for (int i = 0; i < 4; i++)
        #pragma unroll
        for (int j = 0; j < 4; j++) acc[i][j] = z;
    conv_phase1(h, hbase, Gbf, wsp, bas, b, x, tid, acc);
    __syncthreads();   // cbs visible; HOyo free
    const int lane = tid & 63, wave = tid >> 6;
    const int quad = lane >> 4, col = lane & 15;
    #pragma unroll
    for (int mt = 0; mt < 4; mt++) {
        const int o0 = mt * 16 + quad * 4;
        const float c0 = cbs[o0], c1 = cbs[o0 + 1], c2 = cbs[o0 + 2], c3 = cbs[o0 + 3];
        #pragma unroll
        for (int nt = 0; nt < 4; nt++) {
            const int y = wave * 64 + nt * 16 + col;
            uint2 w;
            w.x = pack2bf(gelu_exact(acc[mt][nt][0] + c0), gelu_exact(acc[mt][nt][1] + c1));
            w.y = pack2bf(gelu_exact(acc[mt][nt][2] + c2), gelu_exact(acc[mt][nt][3] + c3));
            *(uint2*)(h + hbase + (long)y * 64 + o0) = w;   // own (b,x) slice only
            *(uint2*)(HOyo + y * HOP + o0) = w;
        }
    }
    __syncthreads();
    f1t_epilogue(HOyo, twf, f1, b, x, tid);
}

// --- K5 (layer 4): conv + fused head, writes d_out only --------------------
__global__ __launch_bounds__(256, 3) void k_conv_head(const u16* __restrict__ h,
                                                      const u16* __restrict__ Gbf,
                                                      const u16* __restrict__ wsp,
                                                      const float* __restrict__ cb,
                                                      const u16* __restrict__ bas,
                                                      const u16* __restrict__ w1sp,
                                                      const float* __restrict__ b1,
                                                      const float* __restrict__ w2,
                                                      const float* __restrict__ b2,
                                                      float* __restrict__ out) {
    __shared__ u16 HOyo[256 * HOP];
    __shared__ float cbs[64], b1s[64], w2s[64];
    const int tid = threadIdx.x;
    const int b = blockIdx.x >> 8, x = blockIdx.x & 255;
    const long hbase = ((long)(b * 256 + x)) << 14;
    if (tid < 64) { cbs[tid] = cb[tid]; b1s[tid] = b1[tid]; w2s[tid] = w2[tid]; }
    const float bias2 = b2[0];
    f32x4 acc[4][4];
    const f32x4 z = {0.f, 0.f, 0.f, 0.f};
    #pragma unroll
    for (int i = 0; i < 4; i++)
        #pragma unroll
        for (int j = 0; j < 4; j++) acc[i][j] = z;
    conv_phase1(h, hbase, Gbf, wsp, bas, b, x, tid, acc);
    __syncthreads();
    const int lane = tid & 63, wave = tid >> 6;
    const int quad = lane >> 4, col = lane & 15;
    #pragma unroll
    for (int mt = 0; mt < 4; mt++) {
        const int o0 = mt * 16 + quad * 4;
        const float c0 = cbs[o0], c1 = cbs[o0 + 1], c2 = cbs[o0 + 2], c3 = cbs[o0 + 3];
        #pragma unroll
        for (int nt = 0; nt < 4; nt++) {
            const int y = wave * 64 + nt * 16 + col;
            uint2 w;
            w.x = pack2bf(gelu_exact(acc[mt][nt][0] + c0), gelu_exact(acc[mt][nt][1] + c1));
            w.y = pack2bf(gelu_exact(acc[mt][nt][2] + c2), gelu_exact(acc[mt][nt][3] + c3));
            *(uint2*)(HOyo + y * HOP + o0) = w;
        }
    }
    __syncthreads();
    // head: D[m=f][n=y], K = o (hi | lo), B from HOyo (vector 8B loads)
    f32x4 acc2[4][4];
    #pragma unroll
    for (int i = 0; i < 4; i++)
        #pragma unroll
        for (int j = 0; j < 4; j++) acc2[i][j] = z;
    #pragma unroll
    for (int ks = 0; ks < 4; ks++) {
        const int kk = (ks & 1) * 32 + quad * 8;
        bf16x8 B[4], A[4];
        #pragma unroll
        for (int nt = 0; nt < 4; nt++) {
            const int y = wave * 64 + nt * 16 + col;
            BU bb;
            bb.u2[0] = *(const uint2*)(HOyo + y * HOP + kk);
            bb.u2[1] = *(const uint2*)(HOyo + y * HOP + kk + 4);
            B[nt] = bb.v;
        }
        #pragma unroll
        for (int mt = 0; mt < 4; mt++)
            A[mt] = *(const bf16x8*)(w1sp + (mt * 16 + col) * 128 + ks * 32 + quad * 8);
        #pragma unroll
        for (int mt = 0; mt < 4; mt++)
            #pragma unroll
            for (int nt = 0; nt < 4; nt++)
                acc2[mt][nt] = __builtin_amdgcn_mfma_f32_16x16x32_bf16(A[mt], B[nt], acc2[mt][nt], 0, 0, 0);
    }
    float p4[4] = {0.f, 0.f, 0.f, 0.f};
    #pragma unroll
    for (int mt = 0; mt < 4; mt++)
        #pragma unroll
        for (int r = 0; r < 4; r++) {
            const int f = mt * 16 + quad * 4 + r;
            const float bb = b1s[f], ww = w2s[f];
            #pragma unroll
            for (int nt = 0; nt < 4; nt++)
                p4[nt] = fmaf(ww, gelu_exact(acc2[mt][nt][r] + bb), p4[nt]);
        }
    #pragma unroll
    for (int nt = 0; nt < 4; nt++) {
        p4[nt] += __shfl_xor(p4[nt], 16);
        p4[nt] += __shfl_xor(p4[nt], 32);
    }
    out[(long)b * 65536 + x * 256 + wave * 64 + lane] = p4[quad] + bias2;
}

extern "C" void kernel_launch(void* const* d_in, const int* in_sizes, int n_in,
                              void* d_out, int out_size, void* d_ws, size_t ws_size,
                              hipStream_t stream) {
    const float* x     = (const float*)d_in[0];
    const float* fc0_w = (const float*)d_in[1];
    const float* fc0_b = (const float*)d_in[2];
    const float* sw[4] = {(const float*)d_in[3], (const float*)d_in[4],
                          (const float*)d_in[5], (const float*)d_in[6]};
    const float* cwA[4] = {(const float*)d_in[7],  (const float*)d_in[9],
                           (const float*)d_in[11], (const float*)d_in[13]};
    const float* cbA[4] = {(const float*)d_in[8],  (const float*)d_in[10],
                           (const float*)d_in[12], (const float*)d_in[14]};
    const float* fc1_w = (const float*)d_in[15];
    const float* fc1_b = (const float*)d_in[16];
    const float* fc2_w = (const float*)d_in[17];
    const float* fc2_b = (const float*)d_in[18];

    char* base = (char*)d_ws;
    u16*   h    = (u16*)base;
    u16*   f1   = (u16*)(base + F1_B);
    u16*   Gbf  = (u16*)(base + G_B);
    float* f2   = (float*)(base + F2_B);
    float* cbuf = (float*)(base + CC_B);
    float* wf   = (float*)(base + WF_B);
    float* wxi  = (float*)(base + WXI_B);
    u16*   twf  = (u16*)(base + TWF_B);
    u16*   bas  = (u16*)(base + BAS_B);
    u16*   wsp  = (u16*)(base + WSP_B);

    k_tab<<<96, 256, 0, stream>>>(wf, wxi, twf, bas);
    k_wsplit<<<80, 256, 0, stream>>>(cwA[0], cwA[1], cwA[2], cwA[3], fc1_w, wsp);
    k_lift<<<4096, 256, 0, stream>>>(x, fc0_w, fc0_b, h, twf, f1);
    for (int l = 0; l < 4; l++) {
        k_dftx<<<1024, 256, 0, stream>>>(f1, wf, f2);
        k_mode<<<256, 256, 0, stream>>>(f2, sw[l], cbuf);
        k_invx<<<1024, 256, 0, stream>>>(cbuf, wxi, Gbf);
        if (l < 3) {
            k_conv<<<4096, 256, 0, stream>>>(h, Gbf, wsp + l * 8192, cbA[l],
                                             bas, twf, f1);
        } else {
            k_conv_head<<<4096, 256, 0, stream>>>(h, Gbf, wsp + 3 * 8192, cbA[3],
                                                  bas, wsp + 4 * 8192, fc1_b,
                                                  fc2_w, fc2_b, (float*)d_out);
        }
    }
}